// Round 7
// baseline (1843.487 us; speedup 1.0000x reference)
//
#include <hip/hip_runtime.h>
#include <stdint.h>
#include <stdio.h>

#define T_TOK 8192
#define HDIM  1024
#define IDIM  3584
#define NEXP  8
#define NPAIR (T_TOK*2)
#define BM 128
#define BN 128
#define BK 32
#define NTK  96   // 3*HDIM/32 K-tiles for the K-concat 3-term GEMM

typedef float          f32x4 __attribute__((ext_vector_type(4)));
typedef short          s16x8 __attribute__((ext_vector_type(8)));
typedef unsigned short u16x4 __attribute__((ext_vector_type(4)));
typedef unsigned short u16x8 __attribute__((ext_vector_type(8)));

__device__ __forceinline__ unsigned short f2bf_rne(float f) {
  unsigned u = __float_as_uint(f);
  u += 0x7FFFu + ((u >> 16) & 1u);
  return (unsigned short)(u >> 16);
}
__device__ __forceinline__ float bf2f(unsigned short h) {
  return __uint_as_float(((unsigned)h) << 16);
}

__device__ __forceinline__ void gld16(const void* gsrc, void* ldst) {
  typedef const unsigned int __attribute__((address_space(1))) GU;
  typedef unsigned int       __attribute__((address_space(3))) LU;
  __builtin_amdgcn_global_load_lds((GU*)(unsigned long long)gsrc,
                                   (LU*)(unsigned int)(unsigned long long)ldst,
                                   16, 0, 0);
}

// ================= K1: split f32 -> (hi, lo) bf16 =================
__global__ void split_hilo(const float* __restrict__ in,
                           unsigned short* __restrict__ hi,
                           unsigned short* __restrict__ lo, int n4) {
  int i = blockIdx.x*blockDim.x + threadIdx.x;
  int s = gridDim.x*blockDim.x;
  for (; i < n4; i += s) {
    f32x4 v = ((const f32x4*)in)[i];
    u16x4 h, l;
#pragma unroll
    for (int j = 0; j < 4; j++) {
      float f = v[j];
      unsigned short hb = f2bf_rne(f);
      h[j] = hb;
      l[j] = f2bf_rne(f - bf2f(hb));
    }
    ((u16x4*)hi)[i] = h;
    ((u16x4*)lo)[i] = l;
  }
}

// ===== K2: transpose W [E][K][N] f32 -> Wt [E][N][K] bf16 hi (+lo optional)
__global__ void transpose_split(const float* __restrict__ W,
                                unsigned short* __restrict__ hi,
                                unsigned short* __restrict__ lo,
                                int K, int N) {
  __shared__ float tile[32][33];
  long base = (long)blockIdx.z * K * N;
  int n0 = blockIdx.x*32, k0 = blockIdx.y*32;
  int tx = threadIdx.x, ty = threadIdx.y; // 32 x 8
#pragma unroll
  for (int r = 0; r < 4; r++)
    tile[ty+8*r][tx] = W[base + (long)(k0+ty+8*r)*N + n0 + tx];
  __syncthreads();
#pragma unroll
  for (int r = 0; r < 4; r++) {
    float f = tile[tx][ty+8*r];
    long o = base + (long)(n0+ty+8*r)*K + k0 + tx;
    unsigned short hb = f2bf_rne(f);
    hi[o] = hb;
    if (lo) lo[o] = f2bf_rne(f - bf2f(hb));
  }
}

// ---- shared top-2 helper (stable, lowest-index tie-break like lax.top_k)
__device__ __forceinline__ void top2_write(const float* acc, int t,
                                           int* __restrict__ topi,
                                           float* __restrict__ topw) {
  int i0 = 0; float l0 = acc[0];
#pragma unroll
  for (int e = 1; e < NEXP; e++) if (acc[e] > l0) { l0 = acc[e]; i0 = e; }
  int i1 = -1; float l1 = -3.4e38f;
#pragma unroll
  for (int e = 0; e < NEXP; e++) if (e != i0 && acc[e] > l1) { l1 = acc[e]; i1 = e; }
  float w0 = 1.f/(1.f + expf(l1 - l0));
  float w1 = 1.f/(1.f + expf(l0 - l1));
  topi[2*t]   = i0; topi[2*t+1] = i1;
  topw[2*t]   = w0; topw[2*t+1] = w1;
}

// ===== K3: fused gate+up router (one pass over x) =========================
__global__ __launch_bounds__(256) void router2_topk(
    const float* __restrict__ X,
    const float* __restrict__ RWg, const float* __restrict__ RWu,
    int* __restrict__ tig, float* __restrict__ twg,
    int* __restrict__ tiu, float* __restrict__ twu) {
  int lane = threadIdx.x & 63;
  int t = blockIdx.x*4 + (threadIdx.x>>6);
  const f32x4* xr = (const f32x4*)(X + (long)t*HDIM);
  float ag[NEXP], au[NEXP];
#pragma unroll
  for (int e = 0; e < NEXP; e++) { ag[e] = 0.f; au[e] = 0.f; }
#pragma unroll
  for (int it = 0; it < HDIM/4/64; it++) {   // 4
    int c4 = it*64 + lane;
    f32x4 xv = xr[c4];
#pragma unroll
    for (int j = 0; j < 4; j++) {
      const float* wg = RWg + (long)(c4*4+j)*NEXP;
      const float* wu = RWu + (long)(c4*4+j)*NEXP;
#pragma unroll
      for (int e = 0; e < NEXP; e++) { ag[e] += xv[j]*wg[e]; au[e] += xv[j]*wu[e]; }
    }
  }
#pragma unroll
  for (int e = 0; e < NEXP; e++) {
    float vg = ag[e], vu = au[e];
#pragma unroll
    for (int o = 1; o < 64; o <<= 1) { vg += __shfl_xor(vg, o); vu += __shfl_xor(vu, o); }
    ag[e] = vg; au[e] = vu;
  }
  if (lane == 0) { top2_write(ag, t, tig, twg); top2_write(au, t, tiu, twu); }
}

// ===== K4: deterministic stable per-expert compaction (1 block per expert)
__global__ __launch_bounds__(256) void build_perm(const int* __restrict__ topi,
                                                  const float* __restrict__ topw,
                                                  int* __restrict__ offs,
                                                  int* __restrict__ ptok,
                                                  float* __restrict__ pw) {
  int e = blockIdx.x;
  int tid = threadIdx.x, lane = tid & 63, wv = tid >> 6;
  __shared__ int cnt[NEXP];
  __shared__ int wsum[4];
  if (tid < NEXP) cnt[tid] = 0;
  __syncthreads();
  for (int p = tid; p < NPAIR; p += 256) atomicAdd(&cnt[topi[p]], 1);
  __syncthreads();
  int base = 0;
#pragma unroll
  for (int e2 = 0; e2 < NEXP; e2++) if (e2 < e) base += cnt[e2];
  if (tid == 0) { offs[e] = base; if (e == NEXP-1) offs[NEXP] = base + cnt[e]; }
  for (int p0 = 0; p0 < NPAIR; p0 += 256) {
    int p = p0 + tid;
    bool m = (topi[p] == e);
    unsigned long long b = __ballot(m);
    int lp = __popcll(b & ((1ull << lane) - 1ull));
    if (lane == 0) wsum[wv] = __popcll(b);
    __syncthreads();
    int woff = 0;
#pragma unroll
    for (int w2 = 0; w2 < 4; w2++) if (w2 < wv) woff += wsum[w2];
    int tot = wsum[0] + wsum[1] + wsum[2] + wsum[3];
    if (m) { int dst = base + woff + lp; ptok[dst] = p >> 1; pw[dst] = topw[p]; }
    base += tot;
    __syncthreads();
  }
}

// ===== K5: gathered 3-term GEMM as K-concat (K'=3072), 256x256 tile =======
// 8 waves (2M x 4N), BK=32, TRIPLE-buffered LDS, counted vmcnt(4) (T4),
// 2 phases/K-tile (T3-min), setprio around MFMA clusters (T5), chunk-rotation
// LDS swizzle with pre-swizzled global source (T2, both-sides rule).
// Safety: buf=t%3 rotation; at end of iter t, vmcnt(4) retires all loads
// except this iter's 4 -> tile t+1 proven landed; tile t+2's in-flight writes
// target a buffer no wave reads until after the NEXT barrier.
__global__ __launch_bounds__(512, 2) void moe_gemm3_8p(
    const unsigned short* __restrict__ Ahi, const unsigned short* __restrict__ Alo,
    const unsigned short* __restrict__ Bhi, const unsigned short* __restrict__ Blo,
    const int* __restrict__ offs, const int* __restrict__ ptok,
    const float* __restrict__ pw, float* __restrict__ out)
{
  const int e = blockIdx.z;
  const int beg = offs[e];
  const int cnt = offs[e+1] - beg;
  const int m0 = blockIdx.y * 256;   // NO XCD swizzle (round-3 lesson)
  if (m0 >= cnt) return;
  const int n0 = blockIdx.x * 256;

  __shared__ unsigned short AsL[3][256*32];   // 3 x 16 KB
  __shared__ unsigned short BsL[3][256*32];   // 3 x 16 KB
  __shared__ int   stok[256];
  __shared__ float swt[256];

  const int tid = threadIdx.x, lane = tid & 63, wv = tid >> 6;
  if (tid < 256) {
    int i = m0 + tid;
    stok[tid] = ptok[beg + (i < cnt ? i : 0)];
    swt[tid]  = (i < cnt) ? pw[beg + i] : 0.f;
  }
  __syncthreads();

  // ---- staging geometry: wave wv owns rows/cols [wv*32, wv*32+32),
  // two 16-row slabs (j=0,1); lane -> (srow, phys 16B chunk).
  const int srow = lane >> 2;                        // 0..15
  const int lc   = ((lane & 3) - ((lane >> 3) & 3)) & 3;  // logical chunk at this phys slot
  const long aoff0 = (long)stok[wv*32 +      srow]*HDIM + lc*8;
  const long aoff1 = (long)stok[wv*32 + 16 + srow]*HDIM + lc*8;
  const long boff0 = ((long)e*IDIM + n0 + wv*32 +      srow)*HDIM + lc*8;
  const long boff1 = ((long)e*IDIM + n0 + wv*32 + 16 + srow)*HDIM + lc*8;
  const int adst0 = (wv*32     )*32;   // shorts
  const int adst1 = (wv*32 + 16)*32;

#define STAGE_A(buf, kt) do {                                              \
    int s_ = (kt) >> 5; int kl_ = ((kt) & 31) * 32;                        \
    const unsigned short* ap_ = (s_ == 1) ? Alo : Ahi;                     \
    gld16(ap_ + aoff0 + kl_, &AsL[buf][adst0]);                            \
    gld16(ap_ + aoff1 + kl_, &AsL[buf][adst1]);                            \
  } while (0)
#define STAGE_B(buf, kt) do {                                              \
    int s_ = (kt) >> 5; int kl_ = ((kt) & 31) * 32;                        \
    const unsigned short* bp_ = (s_ == 2) ? Blo : Bhi;                     \
    gld16(bp_ + boff0 + kl_, &BsL[buf][adst0]);                            \
    gld16(bp_ + boff1 + kl_, &BsL[buf][adst1]);                            \
  } while (0)

  // ---- read-side geometry (16x16x32 frags, verified layout)
  const int fl = lane & 15, fg = lane >> 4;
  const int pks = (((fg + (fl >> 1)) & 3) << 3);     // swizzled k-chunk, shorts
  const int wm = wv >> 2, wn = wv & 3;               // 2M x 4N wave grid
  const int arow = wm * 128;                          // wave's 128 output rows
  const int bcol = wn * 64;                           // wave's 64 output cols

  f32x4 acc[8][4];
#pragma unroll
  for (int m = 0; m < 8; m++)
#pragma unroll
    for (int n = 0; n < 4; n++) acc[m][n] = {0.f, 0.f, 0.f, 0.f};

  // prologue: tiles 0,1 staged and fully landed
  STAGE_A(0, 0); STAGE_B(0, 0);
  STAGE_A(1, 1); STAGE_B(1, 1);
  asm volatile("s_waitcnt vmcnt(0)" ::: "memory");
  __syncthreads();

  int buf = 0, nbuf = 2;
  for (int kt = 0; kt < NTK; ++kt) {
    const bool st = (kt + 2 < NTK);
    s16x8 bhf[4], ahf[4];

    // ---- phase 0: stage A(t+2) | read B + A[0..3] | 16 MFMA
    if (st) STAGE_A(nbuf, kt + 2);
#pragma unroll
    for (int n = 0; n < 4; n++)
      bhf[n] = *(const s16x8*)&BsL[buf][(bcol + n*16 + fl)*32 + pks];
#pragma unroll
    for (int i = 0; i < 4; i++)
      ahf[i] = *(const s16x8*)&AsL[buf][(arow + i*16 + fl)*32 + pks];
    __builtin_amdgcn_s_setprio(1);
#pragma unroll
    for (int i = 0; i < 4; i++)
#pragma unroll
      for (int n = 0; n < 4; n++)
        acc[i][n] = __builtin_amdgcn_mfma_f32_16x16x32_bf16(ahf[i], bhf[n], acc[i][n], 0,0,0);
    __builtin_amdgcn_s_setprio(0);

    // ---- phase 1: stage B(t+2) | read A[4..7] | 16 MFMA
    if (st) STAGE_B(nbuf, kt + 2);
#pragma unroll
    for (int i = 0; i < 4; i++)
      ahf[i] = *(const s16x8*)&AsL[buf][(arow + (4+i)*16 + fl)*32 + pks];
    __builtin_amdgcn_s_setprio(1);
#pragma unroll
    for (int i = 0; i < 4; i++)
#pragma unroll
      for (int n = 0; n < 4; n++)
        acc[4+i][n] = __builtin_amdgcn_mfma_f32_16x16x32_bf16(ahf[i], bhf[n], acc[4+i][n], 0,0,0);
    __builtin_amdgcn_s_setprio(0);

    // ---- tile end: counted drain (never 0 in steady state), raw barrier
    if (st) asm volatile("s_waitcnt vmcnt(4)" ::: "memory");
    else    asm volatile("s_waitcnt vmcnt(0)" ::: "memory");
    __builtin_amdgcn_s_barrier();
    __builtin_amdgcn_sched_barrier(0);

    buf  = (buf  == 2) ? 0 : buf + 1;
    nbuf = (nbuf == 2) ? 0 : nbuf + 1;
  }
#undef STAGE_A
#undef STAGE_B

  // epilogue: C/D map col=lane&15, row=(lane>>4)*4+r  [m89/m91-verified]
#pragma unroll
  for (int m = 0; m < 8; m++)
#pragma unroll
    for (int r = 0; r < 4; r++) {
      int lrow = arow + m*16 + fg*4 + r;
      if (m0 + lrow < cnt) {
        float wt = swt[lrow];
        long ob = (long)stok[lrow]*IDIM + n0 + bcol + fl;
#pragma unroll
        for (int n = 0; n < 4; n++)
          atomicAdd(&out[ob + n*16], wt * acc[m][n][r]);
      }
    }
}

// ===== K6: fused SwiGLU + down-router (h in-place into g, one pass) =======
__global__ __launch_bounds__(256) void swiglu_router(
    float* __restrict__ g, const float* __restrict__ u,
    const float* __restrict__ RW,           // down router [IDIM][NEXP]
    int* __restrict__ topi, float* __restrict__ topw) {
  int lane = threadIdx.x & 63;
  int t = blockIdx.x*4 + (threadIdx.x>>6);
  f32x4*       gr = (f32x4*)(g + (long)t*IDIM);
  const f32x4* ur = (const f32x4*)(u + (long)t*IDIM);
  float acc[NEXP];
#pragma unroll
  for (int e = 0; e < NEXP; e++) acc[e] = 0.f;
#pragma unroll
  for (int it = 0; it < IDIM/4/64; it++) {   // 14
    int c4 = it*64 + lane;
    f32x4 gv = gr[c4], uv = ur[c4], hv;
#pragma unroll
    for (int j = 0; j < 4; j++) {
      float x = gv[j];
      hv[j] = x * uv[j] / (1.f + expf(-x));
    }
    gr[c4] = hv;
#pragma unroll
    for (int j = 0; j < 4; j++) {
      const float* wr = RW + (long)(c4*4+j)*NEXP;
#pragma unroll
      for (int e = 0; e < NEXP; e++) acc[e] += hv[j]*wr[e];
    }
  }
#pragma unroll
  for (int e = 0; e < NEXP; e++) {
    float v = acc[e];
#pragma unroll
    for (int o = 1; o < 64; o <<= 1) v += __shfl_xor(v, o);
    acc[e] = v;
  }
  if (lane == 0) top2_write(acc, t, topi, topw);
}

// ===== K7: down GEMM, 1-term: A = bf16(h), B = Wd_hi bf16 (unchanged) =====
__global__ __launch_bounds__(256) void moe_gemm_down(
    const float* __restrict__ Hf, const unsigned short* __restrict__ Bw,
    const int* __restrict__ offs, const int* __restrict__ ptok,
    const float* __restrict__ pw, float* __restrict__ out)
{
  const int K = IDIM, N = HDIM;
  const int e = blockIdx.z;
  const int beg = offs[e];
  const int cnt = offs[e+1] - beg;
  const int m0 = blockIdx.y * BM;   // NO swizzle
  if (m0 >= cnt) return;
  const int n0 = blockIdx.x * BN;

  __shared__ unsigned short Ah[BM*BK], Bh[BN*BK];
  __shared__ int   stok[BM];
  __shared__ float swt[BM];

  const int tid = threadIdx.x, lane = tid & 63, wv = tid >> 6;
  if (tid < BM) {
    int i = m0 + tid;
    stok[tid] = ptok[beg + (i < cnt ? i : 0)];
    swt[tid]  = (i < cnt) ? pw[beg + i] : 0.f;
  }
  __syncthreads();

  const int arw = tid >> 1, half = tid & 1;
  const float* asrc = Hf + (long)stok[arw]*K + half*16;
  const int awoff = arw*BK + half*16;

  const int srow = lane >> 2, scol = (lane & 3)*8;
  const int r0 = (wv*2+0)*16 + srow, r1 = (wv*2+1)*16 + srow;
  const long b0 = ((long)e*N + n0 + r0)*K + scol;
  const long b1 = ((long)e*N + n0 + r1)*K + scol;
  unsigned short* dB0 = &Bh[(wv*2+0)*16*BK];
  unsigned short* dB1 = &Bh[(wv*2+1)*16*BK];

  f32x4 zero = {0.f,0.f,0.f,0.f};
  f32x4 acc[4][4];
#pragma unroll
  for (int i = 0; i < 4; i++)
#pragma unroll
    for (int j = 0; j < 4; j++) acc[i][j] = zero;

  const int arow = (wv>>1)*64, bcol = (wv&1)*64;
  const int fl = lane & 15, fg = lane >> 4;

  f32x4 p0, p1, p2, p3;
#define LOADA(kk) do {                        \
    p0 = ((const f32x4*)(asrc + (kk)))[0];    \
    p1 = ((const f32x4*)(asrc + (kk)))[1];    \
    p2 = ((const f32x4*)(asrc + (kk)))[2];    \
    p3 = ((const f32x4*)(asrc + (kk)))[3];    \
  } while (0)

  LOADA(0);

  for (int kk = 0; kk < K; kk += BK) {
    __syncthreads();
    gld16(Bw + b0 + kk, dB0);
    gld16(Bw + b1 + kk, dB1);
    u16x8 ha, hb2;
    ha[0]=f2bf_rne(p0[0]); ha[1]=f2bf_rne(p0[1]); ha[2]=f2bf_rne(p0[2]); ha[3]=f2bf_rne(p0[3]);
    ha[4]=f2bf_rne(p1[0]); ha[5]=f2bf_rne(p1[1]); ha[6]=f2bf_rne(p1[2]); ha[7]=f2bf_rne(p1[3]);
    hb2[0]=f2bf_rne(p2[0]); hb2[1]=f2bf_rne(p2[1]); hb2[2]=f2bf_rne(p2[2]); hb2[3]=f2bf_rne(p2[3]);
    hb2[4]=f2bf_rne(p3[0]); hb2[5]=f2bf_rne(p3[1]); hb2[6]=f2bf_rne(p3[2]); hb2[7]=f2bf_rne(p3[3]);
    *(u16x8*)&Ah[awoff]   = ha;
    *(u16x8*)&Ah[awoff+8] = hb2;
    asm volatile("s_waitcnt vmcnt(0)" ::: "memory");
    __syncthreads();

    if (kk + BK < K) LOADA(kk + BK);

    s16x8 ahf[4], bhf[4];
#pragma unroll
    for (int i = 0; i < 4; i++) {
      ahf[i] = *(const s16x8*)&Ah[(arow + i*16 + fl)*BK + fg*8];
      bhf[i] = *(const s16x8*)&Bh[(bcol + i*16 + fl)*BK + fg*8];
    }
#pragma unroll
    for (int i = 0; i < 4; i++)
#pragma unroll
      for (int j = 0; j < 4; j++)
        acc[i][j] = __builtin_amdgcn_mfma_f32_16x16x32_bf16(ahf[i], bhf[j], acc[i][j], 0,0,0);
  }
#undef LOADA

#pragma unroll
  for (int i = 0; i < 4; i++)
#pragma unroll
    for (int r = 0; r < 4; r++) {
      int lrow = arow + i*16 + fg*4 + r;
      if (m0 + lrow < cnt) {
        float wt = swt[lrow];
        long ob = (long)stok[lrow]*N + n0 + bcol + fl;
#pragma unroll
        for (int j = 0; j < 4; j++)
          atomicAdd(&out[ob + j*16], wt * acc[i][j][r]);
      }
    }
}

// ========================== host launcher =================================
// Workspace aliasing (448 MiB avail, peak ~387 MB):
//   ubuf  aliases [wg_hi, wg_lo] — first written AFTER gate GEMM (last wg reader)
//   wd_hi aliases [wu_hi, ...]   — transposed AFTER up GEMM (last wu reader)
extern "C" void kernel_launch(void* const* d_in, const int* in_sizes, int n_in,
                              void* d_out, int out_size, void* d_ws, size_t ws_size,
                              hipStream_t stream)
{
  (void)in_sizes; (void)n_in;
  const float* x   = (const float*)d_in[0];
  const float* grt = (const float*)d_in[1];
  const float* gex = (const float*)d_in[2];
  const float* urt = (const float*)d_in[3];
  const float* uex = (const float*)d_in[4];
  const float* drt = (const float*)d_in[5];
  const float* dex = (const float*)d_in[6];
  float* out = (float*)d_out;

  char* base = (char*)d_ws;
  size_t off = 0;
  auto alloc = [&](size_t b) -> void* {
    void* r = base + off;
    off = (off + b + 255) & ~(size_t)255;
    return r;
  };
  const size_t szXH = (size_t)T_TOK*HDIM*2;
  const size_t szW  = (size_t)NEXP*HDIM*IDIM*2;
  const size_t szGI = (size_t)T_TOK*IDIM*4;

  unsigned short* xhi   = (unsigned short*)alloc(szXH);
  unsigned short* xlo   = (unsigned short*)alloc(szXH);
  unsigned short* wg_hi = (unsigned short*)alloc(szW);   // later: ubuf (f32)
  unsigned short* wg_lo = (unsigned short*)alloc(szW);
  unsigned short* wu_hi = (unsigned short*)alloc(szW);   // later: wd_hi
  unsigned short* wu_lo = (unsigned short*)alloc(szW);
  float* gbuf = (float*)alloc(szGI);
  int*   topi_g = (int*)alloc(NPAIR*4);  float* topw_g = (float*)alloc(NPAIR*4);
  int*   topi_u = (int*)alloc(NPAIR*4);  float* topw_u = (float*)alloc(NPAIR*4);
  int*   topi_d = (int*)alloc(NPAIR*4);  float* topw_d = (float*)alloc(NPAIR*4);
  int* offs_g = (int*)alloc(64);
  int* offs_u = (int*)alloc(64);
  int* offs_d = (int*)alloc(64);
  int*   ptok_g = (int*)alloc(NPAIR*4);  float* pw_g = (float*)alloc(NPAIR*4);
  int*   ptok_u = (int*)alloc(NPAIR*4);  float* pw_u = (float*)alloc(NPAIR*4);
  int*   ptok_d = (int*)alloc(NPAIR*4);  float* pw_d = (float*)alloc(NPAIR*4);

  float*          ubuf  = (float*)wg_hi;
  unsigned short* wd_hi = wu_hi;

  if (off > ws_size) {
    fprintf(stderr, "[moe] ws too small: need %zu bytes, have %zu\n", off, ws_size);
    hipMemsetAsync(d_out, 0, (size_t)out_size*sizeof(float), stream);
    return;
  }

  hipMemsetAsync(gbuf, 0, szGI, stream);
  hipMemsetAsync(d_out, 0, (size_t)out_size*sizeof(float), stream);

  split_hilo<<<2048, 256, 0, stream>>>(x, xhi, xlo, T_TOK*HDIM/4);
  transpose_split<<<dim3(IDIM/32, HDIM/32, NEXP), dim3(32,8), 0, stream>>>(gex, wg_hi, wg_lo, HDIM, IDIM);
  transpose_split<<<dim3(IDIM/32, HDIM/32, NEXP), dim3(32,8), 0, stream>>>(uex, wu_hi, wu_lo, HDIM, IDIM);
  router2_topk<<<T_TOK/4, 256, 0, stream>>>(x, grt, urt, topi_g, topw_g, topi_u, topw_u);
  build_perm<<<NEXP, 256, 0, stream>>>(topi_g, topw_g, offs_g, ptok_g, pw_g);
  build_perm<<<NEXP, 256, 0, stream>>>(topi_u, topw_u, offs_u, ptok_u, pw_u);

  // gate GEMM (last reader of wg region): 256^2 tile, y=64 covers any cnt
  moe_gemm3_8p<<<dim3(IDIM/256, 64, NEXP), 512, 0, stream>>>(
      xhi, xlo, wg_hi, wg_lo, offs_g, ptok_g, pw_g, gbuf);

  // wg region dead -> ubuf
  hipMemsetAsync(ubuf, 0, szGI, stream);
  moe_gemm3_8p<<<dim3(IDIM/256, 64, NEXP), 512, 0, stream>>>(
      xhi, xlo, wu_hi, wu_lo, offs_u, ptok_u, pw_u, ubuf);

  // wu region dead -> wd_hi
  transpose_split<<<dim3(HDIM/32, IDIM/32, NEXP), dim3(32,8), 0, stream>>>(dex, wd_hi, nullptr, IDIM, HDIM);

  // fused: h = silu(g)*u in-place into gbuf + down-router top2
  swiglu_router<<<T_TOK/4, 256, 0, stream>>>(gbuf, ubuf, drt, topi_d, topw_d);
  build_perm<<<NEXP, 256, 0, stream>>>(topi_d, topw_d, offs_d, ptok_d, pw_d);

  moe_gemm_down<<<dim3(HDIM/BN, T_TOK/BM, NEXP), 256, 0, stream>>>(
      gbuf, wd_hi, offs_d, ptok_d, pw_d, out);
}

// Round 8
// 1731.745 us; speedup vs baseline: 1.0645x; 1.0645x over previous
//
#include <hip/hip_runtime.h>
#include <stdint.h>
#include <stdio.h>

#define T_TOK 8192
#define HDIM  1024
#define IDIM  3584
#define NEXP  8
#define NPAIR (T_TOK*2)
#define BM 128
#define BN 128
#define BK 32

typedef float          f32x4 __attribute__((ext_vector_type(4)));
typedef short          s16x8 __attribute__((ext_vector_type(8)));
typedef unsigned short u16x4 __attribute__((ext_vector_type(4)));
typedef unsigned short u16x8 __attribute__((ext_vector_type(8)));

__device__ __forceinline__ unsigned short f2bf_rne(float f) {
  unsigned u = __float_as_uint(f);
  u += 0x7FFFu + ((u >> 16) & 1u);
  return (unsigned short)(u >> 16);
}
__device__ __forceinline__ float bf2f(unsigned short h) {
  return __uint_as_float(((unsigned)h) << 16);
}

__device__ __forceinline__ void gld16(const void* gsrc, void* ldst) {
  typedef const unsigned int __attribute__((address_space(1))) GU;
  typedef unsigned int       __attribute__((address_space(3))) LU;
  __builtin_amdgcn_global_load_lds((GU*)(unsigned long long)gsrc,
                                   (LU*)(unsigned int)(unsigned long long)ldst,
                                   16, 0, 0);
}

// ================= K1: split f32 -> (hi, lo) bf16 =================
__global__ void split_hilo(const float* __restrict__ in,
                           unsigned short* __restrict__ hi,
                           unsigned short* __restrict__ lo, int n4) {
  int i = blockIdx.x*blockDim.x + threadIdx.x;
  int s = gridDim.x*blockDim.x;
  for (; i < n4; i += s) {
    f32x4 v = ((const f32x4*)in)[i];
    u16x4 h, l;
#pragma unroll
    for (int j = 0; j < 4; j++) {
      float f = v[j];
      unsigned short hb = f2bf_rne(f);
      h[j] = hb;
      l[j] = f2bf_rne(f - bf2f(hb));
    }
    ((u16x4*)hi)[i] = h;
    ((u16x4*)lo)[i] = l;
  }
}

// ===== K2: transpose W [E][K][N] f32 -> Wt [E][N][K] bf16 hi (+lo optional)
__global__ void transpose_split(const float* __restrict__ W,
                                unsigned short* __restrict__ hi,
                                unsigned short* __restrict__ lo,
                                int K, int N) {
  __shared__ float tile[32][33];
  long base = (long)blockIdx.z * K * N;
  int n0 = blockIdx.x*32, k0 = blockIdx.y*32;
  int tx = threadIdx.x, ty = threadIdx.y; // 32 x 8
#pragma unroll
  for (int r = 0; r < 4; r++)
    tile[ty+8*r][tx] = W[base + (long)(k0+ty+8*r)*N + n0 + tx];
  __syncthreads();
#pragma unroll
  for (int r = 0; r < 4; r++) {
    float f = tile[tx][ty+8*r];
    long o = base + (long)(n0+ty+8*r)*K + k0 + tx;
    unsigned short hb = f2bf_rne(f);
    hi[o] = hb;
    if (lo) lo[o] = f2bf_rne(f - bf2f(hb));
  }
}

// ---- shared top-2 helper (stable, lowest-index tie-break like lax.top_k)
__device__ __forceinline__ void top2_write(const float* acc, int t,
                                           int* __restrict__ topi,
                                           float* __restrict__ topw) {
  int i0 = 0; float l0 = acc[0];
#pragma unroll
  for (int e = 1; e < NEXP; e++) if (acc[e] > l0) { l0 = acc[e]; i0 = e; }
  int i1 = -1; float l1 = -3.4e38f;
#pragma unroll
  for (int e = 0; e < NEXP; e++) if (e != i0 && acc[e] > l1) { l1 = acc[e]; i1 = e; }
  float w0 = 1.f/(1.f + expf(l1 - l0));
  float w1 = 1.f/(1.f + expf(l0 - l1));
  topi[2*t]   = i0; topi[2*t+1] = i1;
  topw[2*t]   = w0; topw[2*t+1] = w1;
}

// ===== K3: fused gate+up router (one pass over x) =========================
__global__ __launch_bounds__(256) void router2_topk(
    const float* __restrict__ X,
    const float* __restrict__ RWg, const float* __restrict__ RWu,
    int* __restrict__ tig, float* __restrict__ twg,
    int* __restrict__ tiu, float* __restrict__ twu) {
  int lane = threadIdx.x & 63;
  int t = blockIdx.x*4 + (threadIdx.x>>6);
  const f32x4* xr = (const f32x4*)(X + (long)t*HDIM);
  float ag[NEXP], au[NEXP];
#pragma unroll
  for (int e = 0; e < NEXP; e++) { ag[e] = 0.f; au[e] = 0.f; }
#pragma unroll
  for (int it = 0; it < HDIM/4/64; it++) {   // 4
    int c4 = it*64 + lane;
    f32x4 xv = xr[c4];
#pragma unroll
    for (int j = 0; j < 4; j++) {
      const float* wg = RWg + (long)(c4*4+j)*NEXP;
      const float* wu = RWu + (long)(c4*4+j)*NEXP;
#pragma unroll
      for (int e = 0; e < NEXP; e++) { ag[e] += xv[j]*wg[e]; au[e] += xv[j]*wu[e]; }
    }
  }
#pragma unroll
  for (int e = 0; e < NEXP; e++) {
    float vg = ag[e], vu = au[e];
#pragma unroll
    for (int o = 1; o < 64; o <<= 1) { vg += __shfl_xor(vg, o); vu += __shfl_xor(vu, o); }
    ag[e] = vg; au[e] = vu;
  }
  if (lane == 0) { top2_write(ag, t, tig, twg); top2_write(au, t, tiu, twu); }
}

// ===== K4: deterministic stable per-expert compaction (1 block per expert)
__global__ __launch_bounds__(256) void build_perm(const int* __restrict__ topi,
                                                  const float* __restrict__ topw,
                                                  int* __restrict__ offs,
                                                  int* __restrict__ ptok,
                                                  float* __restrict__ pw) {
  int e = blockIdx.x;
  int tid = threadIdx.x, lane = tid & 63, wv = tid >> 6;
  __shared__ int cnt[NEXP];
  __shared__ int wsum[4];
  if (tid < NEXP) cnt[tid] = 0;
  __syncthreads();
  for (int p = tid; p < NPAIR; p += 256) atomicAdd(&cnt[topi[p]], 1);
  __syncthreads();
  int base = 0;
#pragma unroll
  for (int e2 = 0; e2 < NEXP; e2++) if (e2 < e) base += cnt[e2];
  if (tid == 0) { offs[e] = base; if (e == NEXP-1) offs[NEXP] = base + cnt[e]; }
  for (int p0 = 0; p0 < NPAIR; p0 += 256) {
    int p = p0 + tid;
    bool m = (topi[p] == e);
    unsigned long long b = __ballot(m);
    int lp = __popcll(b & ((1ull << lane) - 1ull));
    if (lane == 0) wsum[wv] = __popcll(b);
    __syncthreads();
    int woff = 0;
#pragma unroll
    for (int w2 = 0; w2 < 4; w2++) if (w2 < wv) woff += wsum[w2];
    int tot = wsum[0] + wsum[1] + wsum[2] + wsum[3];
    if (m) { int dst = base + woff + lp; ptok[dst] = p >> 1; pw[dst] = topw[p]; }
    base += tot;
    __syncthreads();
  }
}

// ===== K5: gathered 3-term GEMM, 256x256, MACRO-TILE schedule =============
// Per K-step (32 total): stage ALL 4 planes {Ahi,Alo,Bhi,Blo}[kk] (64KB) into
// a double buffer; run 3 phase-clusters of 32 MFMA from the same LDS copy
// (hi*hi -> hi*lo -> lo*hi). Each plane streamed from HBM exactly ONCE per
// block (fixes round-7's L2 thrash), and the stage for t+1 is issued at the
// START of tile t's ~930-cyc compute (covers ~900cy HBM latency; fixes the
// round-7 barrier stall). Bank swizzle kept (verified: conflicts 3e7 -> 0).
// Safety: writes -> buf^1, reads -> buf, single __syncthreads (compiler
// emits vmcnt(0) lgkmcnt(0) drain) per tile, swap. No counted-vmcnt races.
__global__ __launch_bounds__(512) void moe_gemm3_mt(
    const unsigned short* __restrict__ Ahi, const unsigned short* __restrict__ Alo,
    const unsigned short* __restrict__ Bhi, const unsigned short* __restrict__ Blo,
    const int* __restrict__ offs, const int* __restrict__ ptok,
    const float* __restrict__ pw, float* __restrict__ out)
{
  const int e = blockIdx.z;
  const int beg = offs[e];
  const int cnt = offs[e+1] - beg;
  const int m0 = blockIdx.y * 256;   // NO XCD swizzle (round-3 lesson)
  if (m0 >= cnt) return;
  const int n0 = blockIdx.x * 256;

  __shared__ unsigned short As[2][2][256*32];  // [buf][hi/lo]  64KB
  __shared__ unsigned short Bs[2][2][256*32];  // 64KB
  __shared__ int   stok[256];
  __shared__ float swt[256];

  const int tid = threadIdx.x, lane = tid & 63, wv = tid >> 6;
  if (tid < 256) {
    int i = m0 + tid;
    stok[tid] = ptok[beg + (i < cnt ? i : 0)];
    swt[tid]  = (i < cnt) ? pw[beg + i] : 0.f;
  }
  __syncthreads();

  // staging geometry: wave wv owns rows [wv*32, wv*32+32), two 16-row slabs;
  // lane -> (srow = lane>>2, phys 16B chunk lane&3). Source pre-swizzled:
  // phys chunk p of row r holds logical chunk (p - (r>>1)) & 3.
  const int srow = lane >> 2;
  const int lc   = ((lane & 3) - ((lane >> 3) & 3)) & 3;
  const long aoff0 = (long)stok[wv*32 +      srow]*HDIM + lc*8;
  const long aoff1 = (long)stok[wv*32 + 16 + srow]*HDIM + lc*8;
  const long boff0 = ((long)e*IDIM + n0 + wv*32 +      srow)*HDIM + lc*8;
  const long boff1 = ((long)e*IDIM + n0 + wv*32 + 16 + srow)*HDIM + lc*8;
  const int dst0 = (wv*32     )*32;   // shorts
  const int dst1 = (wv*32 + 16)*32;

#define STAGE_A(buf, kk) do {                                   \
    int kl_ = (kk)*32;                                          \
    gld16(Ahi + aoff0 + kl_, &As[buf][0][dst0]);                \
    gld16(Ahi + aoff1 + kl_, &As[buf][0][dst1]);                \
    gld16(Alo + aoff0 + kl_, &As[buf][1][dst0]);                \
    gld16(Alo + aoff1 + kl_, &As[buf][1][dst1]);                \
  } while (0)
#define STAGE_B(buf, kk) do {                                   \
    int kl_ = (kk)*32;                                          \
    gld16(Bhi + boff0 + kl_, &Bs[buf][0][dst0]);                \
    gld16(Bhi + boff1 + kl_, &Bs[buf][0][dst1]);                \
    gld16(Blo + boff0 + kl_, &Bs[buf][1][dst0]);                \
    gld16(Blo + boff1 + kl_, &Bs[buf][1][dst1]);                \
  } while (0)

  // read-side geometry: lane reads logical k-chunk fg at phys (fg+(fl>>1))&3
  const int fl = lane & 15, fg = lane >> 4;
  const int pks = (((fg + (fl >> 1)) & 3) << 3);     // phys chunk, in shorts
  const int wm = wv >> 2, wn = wv & 3;               // 2M x 4N wave grid
  const int arow = wm * 128;
  const int bcol = wn * 64;

  f32x4 acc[8][4];
#pragma unroll
  for (int m = 0; m < 8; m++)
#pragma unroll
    for (int n = 0; n < 4; n++) acc[m][n] = {0.f, 0.f, 0.f, 0.f};

  STAGE_A(0, 0);
  STAGE_B(0, 0);
  __syncthreads();   // drains vmcnt(0): tile 0 landed

  int cur = 0;
  for (int kt = 0; kt < HDIM/BK; ++kt) {   // 32 macro-tiles
    const bool st = (kt + 1 < HDIM/BK);
    s16x8 ahf[8], bf4[4];

    // phase A: issue A(t+1) | read Ahi[8] + Bhi[4] | 32 MFMA hi*hi
    if (st) STAGE_A(cur^1, kt + 1);
#pragma unroll
    for (int n = 0; n < 4; n++)
      bf4[n] = *(const s16x8*)&Bs[cur][0][(bcol + n*16 + fl)*32 + pks];
#pragma unroll
    for (int i = 0; i < 8; i++)
      ahf[i] = *(const s16x8*)&As[cur][0][(arow + i*16 + fl)*32 + pks];
    __builtin_amdgcn_s_setprio(1);
#pragma unroll
    for (int i = 0; i < 8; i++)
#pragma unroll
      for (int n = 0; n < 4; n++)
        acc[i][n] = __builtin_amdgcn_mfma_f32_16x16x32_bf16(ahf[i], bf4[n], acc[i][n], 0,0,0);
    __builtin_amdgcn_s_setprio(0);

    // phase B: issue B(t+1) | read Blo[4] (Ahi frags still live) | 32 MFMA hi*lo
    if (st) STAGE_B(cur^1, kt + 1);
#pragma unroll
    for (int n = 0; n < 4; n++)
      bf4[n] = *(const s16x8*)&Bs[cur][1][(bcol + n*16 + fl)*32 + pks];
    __builtin_amdgcn_s_setprio(1);
#pragma unroll
    for (int i = 0; i < 8; i++)
#pragma unroll
      for (int n = 0; n < 4; n++)
        acc[i][n] = __builtin_amdgcn_mfma_f32_16x16x32_bf16(ahf[i], bf4[n], acc[i][n], 0,0,0);
    __builtin_amdgcn_s_setprio(0);

    // phase C: read Alo[8] (overwrites ahf) + re-read Bhi[4] | 32 MFMA lo*hi
#pragma unroll
    for (int i = 0; i < 8; i++)
      ahf[i] = *(const s16x8*)&As[cur][1][(arow + i*16 + fl)*32 + pks];
#pragma unroll
    for (int n = 0; n < 4; n++)
      bf4[n] = *(const s16x8*)&Bs[cur][0][(bcol + n*16 + fl)*32 + pks];
    __builtin_amdgcn_s_setprio(1);
#pragma unroll
    for (int i = 0; i < 8; i++)
#pragma unroll
      for (int n = 0; n < 4; n++)
        acc[i][n] = __builtin_amdgcn_mfma_f32_16x16x32_bf16(ahf[i], bf4[n], acc[i][n], 0,0,0);
    __builtin_amdgcn_s_setprio(0);

    __syncthreads();   // drain: t+1's 8 loads landed; everyone done with cur
    cur ^= 1;
  }
#undef STAGE_A
#undef STAGE_B

  // epilogue: C/D map col=lane&15, row=(lane>>4)*4+r  [m89/m91-verified]
#pragma unroll
  for (int m = 0; m < 8; m++)
#pragma unroll
    for (int r = 0; r < 4; r++) {
      int lrow = arow + m*16 + fg*4 + r;
      if (m0 + lrow < cnt) {
        float wt = swt[lrow];
        long ob = (long)stok[lrow]*IDIM + n0 + bcol + fl;
#pragma unroll
        for (int n = 0; n < 4; n++)
          atomicAdd(&out[ob + n*16], wt * acc[m][n][r]);
      }
    }
}

// ===== K6: fused SwiGLU + down-router (h in-place into g, one pass) =======
__global__ __launch_bounds__(256) void swiglu_router(
    float* __restrict__ g, const float* __restrict__ u,
    const float* __restrict__ RW,           // down router [IDIM][NEXP]
    int* __restrict__ topi, float* __restrict__ topw) {
  int lane = threadIdx.x & 63;
  int t = blockIdx.x*4 + (threadIdx.x>>6);
  f32x4*       gr = (f32x4*)(g + (long)t*IDIM);
  const f32x4* ur = (const f32x4*)(u + (long)t*IDIM);
  float acc[NEXP];
#pragma unroll
  for (int e = 0; e < NEXP; e++) acc[e] = 0.f;
#pragma unroll
  for (int it = 0; it < IDIM/4/64; it++) {   // 14
    int c4 = it*64 + lane;
    f32x4 gv = gr[c4], uv = ur[c4], hv;
#pragma unroll
    for (int j = 0; j < 4; j++) {
      float x = gv[j];
      hv[j] = x * uv[j] / (1.f + expf(-x));
    }
    gr[c4] = hv;
#pragma unroll
    for (int j = 0; j < 4; j++) {
      const float* wr = RW + (long)(c4*4+j)*NEXP;
#pragma unroll
      for (int e = 0; e < NEXP; e++) acc[e] += hv[j]*wr[e];
    }
  }
#pragma unroll
  for (int e = 0; e < NEXP; e++) {
    float v = acc[e];
#pragma unroll
    for (int o = 1; o < 64; o <<= 1) v += __shfl_xor(v, o);
    acc[e] = v;
  }
  if (lane == 0) top2_write(acc, t, topi, topw);
}

// ===== K7: down GEMM, 1-term: A = bf16(h), B = Wd_hi bf16 (unchanged) =====
__global__ __launch_bounds__(256) void moe_gemm_down(
    const float* __restrict__ Hf, const unsigned short* __restrict__ Bw,
    const int* __restrict__ offs, const int* __restrict__ ptok,
    const float* __restrict__ pw, float* __restrict__ out)
{
  const int K = IDIM, N = HDIM;
  const int e = blockIdx.z;
  const int beg = offs[e];
  const int cnt = offs[e+1] - beg;
  const int m0 = blockIdx.y * BM;   // NO swizzle
  if (m0 >= cnt) return;
  const int n0 = blockIdx.x * BN;

  __shared__ unsigned short Ah[BM*BK], Bh[BN*BK];
  __shared__ int   stok[BM];
  __shared__ float swt[BM];

  const int tid = threadIdx.x, lane = tid & 63, wv = tid >> 6;
  if (tid < BM) {
    int i = m0 + tid;
    stok[tid] = ptok[beg + (i < cnt ? i : 0)];
    swt[tid]  = (i < cnt) ? pw[beg + i] : 0.f;
  }
  __syncthreads();

  const int arw = tid >> 1, half = tid & 1;
  const float* asrc = Hf + (long)stok[arw]*K + half*16;
  const int awoff = arw*BK + half*16;

  const int srow = lane >> 2, scol = (lane & 3)*8;
  const int r0 = (wv*2+0)*16 + srow, r1 = (wv*2+1)*16 + srow;
  const long b0 = ((long)e*N + n0 + r0)*K + scol;
  const long b1 = ((long)e*N + n0 + r1)*K + scol;
  unsigned short* dB0 = &Bh[(wv*2+0)*16*BK];
  unsigned short* dB1 = &Bh[(wv*2+1)*16*BK];

  f32x4 zero = {0.f,0.f,0.f,0.f};
  f32x4 acc[4][4];
#pragma unroll
  for (int i = 0; i < 4; i++)
#pragma unroll
    for (int j = 0; j < 4; j++) acc[i][j] = zero;

  const int arow = (wv>>1)*64, bcol = (wv&1)*64;
  const int fl = lane & 15, fg = lane >> 4;

  f32x4 p0, p1, p2, p3;
#define LOADA(kk) do {                        \
    p0 = ((const f32x4*)(asrc + (kk)))[0];    \
    p1 = ((const f32x4*)(asrc + (kk)))[1];    \
    p2 = ((const f32x4*)(asrc + (kk)))[2];    \
    p3 = ((const f32x4*)(asrc + (kk)))[3];    \
  } while (0)

  LOADA(0);

  for (int kk = 0; kk < K; kk += BK) {
    __syncthreads();
    gld16(Bw + b0 + kk, dB0);
    gld16(Bw + b1 + kk, dB1);
    u16x8 ha, hb2;
    ha[0]=f2bf_rne(p0[0]); ha[1]=f2bf_rne(p0[1]); ha[2]=f2bf_rne(p0[2]); ha[3]=f2bf_rne(p0[3]);
    ha[4]=f2bf_rne(p1[0]); ha[5]=f2bf_rne(p1[1]); ha[6]=f2bf_rne(p1[2]); ha[7]=f2bf_rne(p1[3]);
    hb2[0]=f2bf_rne(p2[0]); hb2[1]=f2bf_rne(p2[1]); hb2[2]=f2bf_rne(p2[2]); hb2[3]=f2bf_rne(p2[3]);
    hb2[4]=f2bf_rne(p3[0]); hb2[5]=f2bf_rne(p3[1]); hb2[6]=f2bf_rne(p3[2]); hb2[7]=f2bf_rne(p3[3]);
    *(u16x8*)&Ah[awoff]   = ha;
    *(u16x8*)&Ah[awoff+8] = hb2;
    asm volatile("s_waitcnt vmcnt(0)" ::: "memory");
    __syncthreads();

    if (kk + BK < K) LOADA(kk + BK);

    s16x8 ahf[4], bhf[4];
#pragma unroll
    for (int i = 0; i < 4; i++) {
      ahf[i] = *(const s16x8*)&Ah[(arow + i*16 + fl)*BK + fg*8];
      bhf[i] = *(const s16x8*)&Bh[(bcol + i*16 + fl)*BK + fg*8];
    }
#pragma unroll
    for (int i = 0; i < 4; i++)
#pragma unroll
      for (int j = 0; j < 4; j++)
        acc[i][j] = __builtin_amdgcn_mfma_f32_16x16x32_bf16(ahf[i], bhf[j], acc[i][j], 0,0,0);
  }
#undef LOADA

#pragma unroll
  for (int i = 0; i < 4; i++)
#pragma unroll
    for (int r = 0; r < 4; r++) {
      int lrow = arow + i*16 + fg*4 + r;
      if (m0 + lrow < cnt) {
        float wt = swt[lrow];
        long ob = (long)stok[lrow]*N + n0 + bcol + fl;
#pragma unroll
        for (int j = 0; j < 4; j++)
          atomicAdd(&out[ob + j*16], wt * acc[i][j][r]);
      }
    }
}

// ========================== host launcher =================================
// Workspace aliasing (448 MiB avail, peak ~387 MB):
//   ubuf  aliases [wg_hi, wg_lo] — first written AFTER gate GEMM (last wg reader)
//   wd_hi aliases [wu_hi, ...]   — transposed AFTER up GEMM (last wu reader)
extern "C" void kernel_launch(void* const* d_in, const int* in_sizes, int n_in,
                              void* d_out, int out_size, void* d_ws, size_t ws_size,
                              hipStream_t stream)
{
  (void)in_sizes; (void)n_in;
  const float* x   = (const float*)d_in[0];
  const float* grt = (const float*)d_in[1];
  const float* gex = (const float*)d_in[2];
  const float* urt = (const float*)d_in[3];
  const float* uex = (const float*)d_in[4];
  const float* drt = (const float*)d_in[5];
  const float* dex = (const float*)d_in[6];
  float* out = (float*)d_out;

  char* base = (char*)d_ws;
  size_t off = 0;
  auto alloc = [&](size_t b) -> void* {
    void* r = base + off;
    off = (off + b + 255) & ~(size_t)255;
    return r;
  };
  const size_t szXH = (size_t)T_TOK*HDIM*2;
  const size_t szW  = (size_t)NEXP*HDIM*IDIM*2;
  const size_t szGI = (size_t)T_TOK*IDIM*4;

  unsigned short* xhi   = (unsigned short*)alloc(szXH);
  unsigned short* xlo   = (unsigned short*)alloc(szXH);
  unsigned short* wg_hi = (unsigned short*)alloc(szW);   // later: ubuf (f32)
  unsigned short* wg_lo = (unsigned short*)alloc(szW);
  unsigned short* wu_hi = (unsigned short*)alloc(szW);   // later: wd_hi
  unsigned short* wu_lo = (unsigned short*)alloc(szW);
  float* gbuf = (float*)alloc(szGI);
  int*   topi_g = (int*)alloc(NPAIR*4);  float* topw_g = (float*)alloc(NPAIR*4);
  int*   topi_u = (int*)alloc(NPAIR*4);  float* topw_u = (float*)alloc(NPAIR*4);
  int*   topi_d = (int*)alloc(NPAIR*4);  float* topw_d = (float*)alloc(NPAIR*4);
  int* offs_g = (int*)alloc(64);
  int* offs_u = (int*)alloc(64);
  int* offs_d = (int*)alloc(64);
  int*   ptok_g = (int*)alloc(NPAIR*4);  float* pw_g = (float*)alloc(NPAIR*4);
  int*   ptok_u = (int*)alloc(NPAIR*4);  float* pw_u = (float*)alloc(NPAIR*4);
  int*   ptok_d = (int*)alloc(NPAIR*4);  float* pw_d = (float*)alloc(NPAIR*4);

  float*          ubuf  = (float*)wg_hi;
  unsigned short* wd_hi = wu_hi;

  if (off > ws_size) {
    fprintf(stderr, "[moe] ws too small: need %zu bytes, have %zu\n", off, ws_size);
    hipMemsetAsync(d_out, 0, (size_t)out_size*sizeof(float), stream);
    return;
  }

  hipMemsetAsync(gbuf, 0, szGI, stream);
  hipMemsetAsync(d_out, 0, (size_t)out_size*sizeof(float), stream);

  split_hilo<<<2048, 256, 0, stream>>>(x, xhi, xlo, T_TOK*HDIM/4);
  transpose_split<<<dim3(IDIM/32, HDIM/32, NEXP), dim3(32,8), 0, stream>>>(gex, wg_hi, wg_lo, HDIM, IDIM);
  transpose_split<<<dim3(IDIM/32, HDIM/32, NEXP), dim3(32,8), 0, stream>>>(uex, wu_hi, wu_lo, HDIM, IDIM);
  router2_topk<<<T_TOK/4, 256, 0, stream>>>(x, grt, urt, topi_g, topw_g, topi_u, topw_u);
  build_perm<<<NEXP, 256, 0, stream>>>(topi_g, topw_g, offs_g, ptok_g, pw_g);
  build_perm<<<NEXP, 256, 0, stream>>>(topi_u, topw_u, offs_u, ptok_u, pw_u);

  // gate GEMM (last reader of wg region): 256^2 tile; y=32 covers cnt<=8192
  moe_gemm3_mt<<<dim3(IDIM/256, 32, NEXP), 512, 0, stream>>>(
      xhi, xlo, wg_hi, wg_lo, offs_g, ptok_g, pw_g, gbuf);

  // wg region dead -> ubuf
  hipMemsetAsync(ubuf, 0, szGI, stream);
  moe_gemm3_mt<<<dim3(IDIM/256, 32, NEXP), 512, 0, stream>>>(
      xhi, xlo, wu_hi, wu_lo, offs_u, ptok_u, pw_u, ubuf);

  // wu region dead -> wd_hi
  transpose_split<<<dim3(HDIM/32, IDIM/32, NEXP), dim3(32,8), 0, stream>>>(dex, wd_hi, nullptr, IDIM, HDIM);

  // fused: h = silu(g)*u in-place into gbuf + down-router top2
  swiglu_router<<<T_TOK/4, 256, 0, stream>>>(gbuf, ubuf, drt, topi_d, topw_d);
  build_perm<<<NEXP, 256, 0, stream>>>(topi_d, topw_d, offs_d, ptok_d, pw_d);

  moe_gemm_down<<<dim3(HDIM/BN, T_TOK/BM, NEXP), 256, 0, stream>>>(
      gbuf, wd_hi, offs_d, ptok_d, pw_d, out);
}